// Round 5
// baseline (777.389 us; speedup 1.0000x reference)
//
#include <hip/hip_runtime.h>

// UAG-RNN 4-neighbor — round 8: 2-kernel chunked-pipeline design.
//
// Diagnosis r1-r4: per-step envelope (~1100-1450cyc) across ALL variants is
// the __syncthreads vmcnt(0) drain of per-step global loads/stores (plus
// per-step barrier cost), not the broadcast mechanism. Fix: chunk the scan
// into 32-step phases; all VMEM is done by helper waves a chunk ahead/behind;
// the recurrence wave does pure LDS+VALU with same-wave lgkm ordering and no
// barriers inside a chunk. One __syncthreads per 32 steps.
//
//  scan1 (x -> ws):  3 waves/block, block = (b, w) column chain.
//    CA (wave2): chunk k:   gather x[b][c][h][w] (lane=c, 64-line gather;
//                x is L3-resident, lines shared by 16 w-neighbors) ->
//                broadcast via xb -> aterm = W1*x + b1 + b2 -> xs[k&1].
//                (k==0,i==0: raw x passthrough, reference row-0 semantics.)
//    P  (wave0): chunk k-1: v = relu(aterm + W2*v), broadcast via the vh
//                state ring itself (ds_write then 16 uniform ds_read_b128,
//                same-wave in-order, no barrier). Zero VMEM.
//    CB (wave1): chunk k-2: u = W4*v + b4 + b5 (w==0: u = raw v) ->
//                A2[b][h][w][o], coalesced 256B rows.
//  scan2 (ws -> out): 2 waves/block, block = (b, h) row chain.
//    CA: stage A2 chunk ahead (coalesced). P: v = relu(aterm + W5*v),
//    sh[] broadcast, 16-step register output batches -> 64B/lane stores.
//
// A2 layout (as r6/r7, proven): A2[b][h][w][o]; out final [b][c][h][w].

#define C64 64
#define S   384

typedef float v2f __attribute__((ext_vector_type(2)));

static __device__ __forceinline__ v2f mk2(float a, float b) {
    v2f r; r.x = a; r.y = b; return r;
}

// acc = INIT + M * broadcast_row  (16 v2f pk_fma, 4 chains)
#define MATVEC(DST, WREG, VQ4, INIT)                                          \
    float DST;                                                                \
    {                                                                         \
        v2f a0 = mk2((INIT), 0.f), a1 = mk2(0.f,0.f),                         \
            a2v = mk2(0.f,0.f),    a3 = mk2(0.f,0.f);                         \
        _Pragma("unroll")                                                     \
        for (int i_ = 0; i_ < 8; ++i_) {                                      \
            float4 r0 = (VQ4)[2*i_], r1 = (VQ4)[2*i_+1];                      \
            a0  = __builtin_elementwise_fma(WREG[4*i_+0], mk2(r0.x,r0.y), a0);\
            a1  = __builtin_elementwise_fma(WREG[4*i_+1], mk2(r0.z,r0.w), a1);\
            a2v = __builtin_elementwise_fma(WREG[4*i_+2], mk2(r1.x,r1.y), a2v);\
            a3  = __builtin_elementwise_fma(WREG[4*i_+3], mk2(r1.z,r1.w), a3);\
        }                                                                     \
        v2f sv = (a0 + a1) + (a2v + a3);                                      \
        DST = sv.x + sv.y;                                                    \
    }

#define LOADW(WSEL)                                                           \
    {                                                                         \
        const float4* P4_ = (const float4*)((WSEL) + o * C64);                \
        _Pragma("unroll")                                                     \
        for (int i_ = 0; i_ < 16; ++i_) {                                     \
            float4 u_ = P4_[i_];                                              \
            wr2[2*i_+0] = mk2(u_.x, u_.y);                                    \
            wr2[2*i_+1] = mk2(u_.z, u_.w);                                    \
        }                                                                     \
        _Pragma("unroll")                                                     \
        for (int i_ = 0; i_ < 32; ++i_) asm volatile("" : "+v"(wr2[i_]));     \
    }

// ---------------------------------------------------------------------------
// scan1: vertical recurrence, prelin fused (CA) + A2 producer (CB).
// ---------------------------------------------------------------------------
__global__ __launch_bounds__(192, 3)
void scan1_kernel(const float* __restrict__ X, float* __restrict__ A2,
                  const float* __restrict__ W1, const float* __restrict__ b1,
                  const float* __restrict__ b2, const float* __restrict__ W2,
                  const float* __restrict__ W4, const float* __restrict__ b4,
                  const float* __restrict__ b5)
{
    __shared__ float vh[2][32][C64];   // state ring (P writes, CB reads)
    __shared__ float xs[2][32][C64];   // aterm ring (CA writes, P reads)
    __shared__ float xb[2][C64];       // CA broadcast staging

    const int t = threadIdx.x, wid = t >> 6, o = t & 63;
    const int g = blockIdx.x, b = g / S, w = g - b * S;
    const bool w_is0 = (w == 0);

    v2f wr2[32];
    const float* Wsel = (wid == 0) ? W2 : (wid == 1) ? W4 : W1;
    LOADW(Wsel)

    float bias = 0.f;
    if (wid == 1) bias = b4[o] + b5[o];
    if (wid == 2) bias = b1[o] + b2[o];

    const int xbase  = ((b * C64 + o) * S) * S + w;   // lane = channel (CA)
    const int a2base = (b * S * S + w) * C64 + o;     // + h*(S*C64)   (CB)

    for (int p = 0; p < 14; ++p) {
        if (wid == 2) {                       // ---- CA: chunk k = p ----
            if (p < 12) {
                const int k = p, cb = k & 1, hb = 32 * k;
                float xg[32];
#pragma unroll
                for (int i = 0; i < 32; ++i)
                    xg[i] = X[xbase + (hb + i) * S];
#pragma unroll
                for (int i = 0; i < 32; ++i) {
                    xb[i & 1][o] = xg[i];
                    const float4* q4 = (const float4*)&xb[i & 1][0];
                    MATVEC(a_, wr2, q4, bias)
                    float val = a_;
                    if (i == 0 && k == 0) val = xg[0];   // raw row 0
                    xs[cb][i][o] = val;
                }
            }
        } else if (wid == 0) {                // ---- P: chunk m = p-1 ----
            if (p >= 1 && p < 13) {
                const int m = p - 1, cb = m & 1;
                if (m == 0) {
                    vh[0][0][o] = xs[0][0][o];          // v_0 raw, no relu
                } else {
                    const float4* q4 = (const float4*)&vh[cb ^ 1][31][0];
                    float a_t = xs[cb][0][o];
                    MATVEC(s_, wr2, q4, a_t)
                    vh[cb][0][o] = fmaxf(s_, 0.0f);
                }
#pragma unroll 2
                for (int i = 1; i < 32; ++i) {
                    const float4* q4 = (const float4*)&vh[cb][i - 1][0];
                    float a_t = xs[cb][i][o];
                    MATVEC(s_, wr2, q4, a_t)
                    vh[cb][i][o] = fmaxf(s_, 0.0f);
                }
            }
        } else {                              // ---- CB: chunk m = p-2 ----
            if (p >= 2) {
                const int m = p - 2, cb = m & 1, hb = 32 * m;
#pragma unroll 2
                for (int j = 0; j < 32; ++j) {
                    const float4* q4 = (const float4*)&vh[cb][j][0];
                    MATVEC(u_, wr2, q4, bias)
                    float vraw = vh[cb][j][o];
                    float uo = w_is0 ? vraw : u_;
                    A2[a2base + (hb + j) * (S * C64)] = uo;
                }
            }
        }
        __syncthreads();
    }
}

// ---------------------------------------------------------------------------
// scan2: horizontal recurrence; CA stages coalesced A2 chunks one ahead.
// ---------------------------------------------------------------------------
__global__ __launch_bounds__(128, 3)
void scan2_kernel(const float* __restrict__ A2, float* __restrict__ out,
                  const float* __restrict__ W5)
{
    __shared__ float xs[2][32][C64];
    __shared__ float sh[C64];

    const int t = threadIdx.x, wid = t >> 6, o = t & 63;
    const int g = blockIdx.x, b = g / S, hr = g - b * S;

    const int abase = ((b * S + hr) * S) * C64 + o;   // + w*C64
    const int outb  = ((b * C64 + o) * S + hr) * S;   // + w

    v2f wr2[32];
    if (wid == 0) { LOADW(W5) }

    float v = 0.f;
    float ob[16];

#define STEP2(I, IDX)                                                         \
    {                                                                         \
        float a_t = xs[cb][I][o];                                             \
        sh[o] = v;                                                            \
        const float4* q4_ = (const float4*)&sh[0];                            \
        MATVEC(s_, wr2, q4_, a_t)                                             \
        v = fmaxf(s_, 0.0f);                                                  \
        ob[IDX] = v;                                                          \
    }
#define STORE16(BASE)                                                         \
    {                                                                         \
        float4 s0 = {ob[0],  ob[1],  ob[2],  ob[3]};                          \
        float4 s1 = {ob[4],  ob[5],  ob[6],  ob[7]};                          \
        float4 s2 = {ob[8],  ob[9],  ob[10], ob[11]};                         \
        float4 s3 = {ob[12], ob[13], ob[14], ob[15]};                         \
        float4* pp = (float4*)(out + outb + (BASE));                          \
        pp[0] = s0; pp[1] = s1; pp[2] = s2; pp[3] = s3;                       \
    }

    for (int p = 0; p < 13; ++p) {
        if (wid == 1) {                       // ---- CA: chunk k = p ----
            if (p < 12) {
                const int k = p, cb = k & 1, wb = 32 * k;
                float gx[32];
#pragma unroll
                for (int i = 0; i < 32; ++i)
                    gx[i] = A2[abase + (wb + i) * C64];
#pragma unroll
                for (int i = 0; i < 32; ++i)
                    xs[cb][i][o] = gx[i];
            }
        } else {                              // ---- P: chunk m = p-1 ----
            if (p >= 1) {
                const int m = p - 1, cb = m & 1;
                if (m == 0) {
                    v = fmaxf(xs[0][0][o], 0.0f);       // relu on col 0
                    ob[0] = v;
                    STEP2( 1, 1) STEP2( 2, 2) STEP2( 3, 3) STEP2( 4, 4)
                    STEP2( 5, 5) STEP2( 6, 6) STEP2( 7, 7) STEP2( 8, 8)
                    STEP2( 9, 9) STEP2(10,10) STEP2(11,11) STEP2(12,12)
                    STEP2(13,13) STEP2(14,14) STEP2(15,15)
                } else {
                    STEP2( 0, 0) STEP2( 1, 1) STEP2( 2, 2) STEP2( 3, 3)
                    STEP2( 4, 4) STEP2( 5, 5) STEP2( 6, 6) STEP2( 7, 7)
                    STEP2( 8, 8) STEP2( 9, 9) STEP2(10,10) STEP2(11,11)
                    STEP2(12,12) STEP2(13,13) STEP2(14,14) STEP2(15,15)
                }
                STORE16(32 * m)
                STEP2(16, 0) STEP2(17, 1) STEP2(18, 2) STEP2(19, 3)
                STEP2(20, 4) STEP2(21, 5) STEP2(22, 6) STEP2(23, 7)
                STEP2(24, 8) STEP2(25, 9) STEP2(26,10) STEP2(27,11)
                STEP2(28,12) STEP2(29,13) STEP2(30,14) STEP2(31,15)
                STORE16(32 * m + 16)
            }
        }
        __syncthreads();
    }
#undef STEP2
#undef STORE16
}

extern "C" void kernel_launch(void* const* d_in, const int* in_sizes, int n_in,
                              void* d_out, int out_size, void* d_ws, size_t ws_size,
                              hipStream_t stream) {
    const float* x  = (const float*)d_in[0];
    const float* W1 = (const float*)d_in[1];
    const float* b1 = (const float*)d_in[2];
    const float* W2 = (const float*)d_in[3];
    const float* b2 = (const float*)d_in[4];
    const float* W4 = (const float*)d_in[5];
    const float* b4 = (const float*)d_in[6];
    const float* W5 = (const float*)d_in[7];
    const float* b5 = (const float*)d_in[8];
    float* out = (float*)d_out;
    float* ws  = (float*)d_ws;     // A2: B*S*S*C floats

    scan1_kernel<<<dim3(4 * S), dim3(192), 0, stream>>>(x, ws, W1, b1, b2,
                                                        W2, W4, b4, b5);
    scan2_kernel<<<dim3(4 * S), dim3(128), 0, stream>>>(ws, out, W5);
}

// Round 6
// 743.253 us; speedup vs baseline: 1.0459x; 1.0459x over previous
//
#include <hip/hip_runtime.h>

// UAG-RNN 4-neighbor — round 9: register-headroom fix.
//
// Root cause found (r1-r5 cross-eval): after 64 pinned weight floats, every
// scan variant left the matvec's 16 ds_read_b128 only ~4-8 free VGPRs ->
// compiler serialized read->lgkmcnt(0)->fma per read = 16 x ~120cy = the
// stubborn ~1200-2500 cy/step floor (VGPR_Count 60/72/68 across rounds).
// prelin's input vector likewise spilled (VGPR=48 < 64 floats) -> 190us.
// Fix: every matvec gets a dedicated 16xfloat4 (or 2x8) register read batch
// under one lgkm wait; weight sets capped at 64 floats/wave.
//
//  prelin (x -> out):  A1[b][w][h][o] = W1*x[:,h,w]+b1+b2 (h>=1; h==0 raw).
//     4 waves/block, wave computes 16 outputs, c-blocked (32 in + 32 acc
//     live), LDS transpose, full-line stores.
//  scan1 (out -> ws):  v_h = relu(A1[h] + W2*v_{h-1}); 1 wave/chain, no
//     barriers; per-step coalesced 256B store of RAW v -> hsT[b][h][w][o].
//  scan2 (ws -> out):  chunked CA+P. CA: coalesced hsT rows -> aterm =
//     W4*row+b4+b5 (w==0 raw). P: v_w = relu(aterm + W5*v_{w-1}) with
//     v_{-1}=0 (so w==0 needs no special case), 16-step line-batched stores.

#define C64 64
#define S   384

typedef float v2f __attribute__((ext_vector_type(2)));

static __device__ __forceinline__ v2f mk2(float a, float b) {
    v2f r; r.x = a; r.y = b; return r;
}

// ---- batched LDS broadcast matvec, 16 reads in one batch (scan1) ----
#define LOADRB16(SRC)                                                         \
    float4 rb[16];                                                            \
    {                                                                         \
        const float4* vq4_ = (const float4*)(SRC);                            \
        _Pragma("unroll")                                                     \
        for (int i_ = 0; i_ < 16; ++i_) rb[i_] = vq4_[i_];                    \
    }
#define MATVEC16(DST, WREG, INIT)                                             \
    float DST;                                                                \
    {                                                                         \
        v2f a0 = mk2((INIT), 0.f), a1 = mk2(0.f,0.f),                         \
            a2v = mk2(0.f,0.f),    a3 = mk2(0.f,0.f);                         \
        _Pragma("unroll")                                                     \
        for (int i_ = 0; i_ < 8; ++i_) {                                      \
            float4 r0 = rb[2*i_], r1 = rb[2*i_+1];                            \
            a0  = __builtin_elementwise_fma(WREG[4*i_+0], mk2(r0.x,r0.y), a0);\
            a1  = __builtin_elementwise_fma(WREG[4*i_+1], mk2(r0.z,r0.w), a1);\
            a2v = __builtin_elementwise_fma(WREG[4*i_+2], mk2(r1.x,r1.y), a2v);\
            a3  = __builtin_elementwise_fma(WREG[4*i_+3], mk2(r1.z,r1.w), a3);\
        }                                                                     \
        v2f sv = (a0 + a1) + (a2v + a3);                                      \
        DST = sv.x + sv.y;                                                    \
    }

// ---- half-batched variant (2 x 8 reads) for scan2 (saves 32 VGPR) ----
#define MATVEC_H(DST, WREG, SRC, INIT)                                        \
    float DST;                                                                \
    {                                                                         \
        const float4* vq4_ = (const float4*)(SRC);                            \
        v2f a0 = mk2((INIT), 0.f), a1 = mk2(0.f,0.f),                         \
            a2v = mk2(0.f,0.f),    a3 = mk2(0.f,0.f);                         \
        _Pragma("unroll")                                                     \
        for (int h_ = 0; h_ < 2; ++h_) {                                      \
            float4 rb8[8];                                                    \
            _Pragma("unroll")                                                 \
            for (int i_ = 0; i_ < 8; ++i_) rb8[i_] = vq4_[8*h_ + i_];         \
            _Pragma("unroll")                                                 \
            for (int i_ = 0; i_ < 4; ++i_) {                                  \
                float4 r0 = rb8[2*i_], r1 = rb8[2*i_+1];                      \
                a0  = __builtin_elementwise_fma(WREG[16*h_+4*i_+0],           \
                                                mk2(r0.x,r0.y), a0);          \
                a1  = __builtin_elementwise_fma(WREG[16*h_+4*i_+1],           \
                                                mk2(r0.z,r0.w), a1);          \
                a2v = __builtin_elementwise_fma(WREG[16*h_+4*i_+2],           \
                                                mk2(r1.x,r1.y), a2v);         \
                a3  = __builtin_elementwise_fma(WREG[16*h_+4*i_+3],           \
                                                mk2(r1.z,r1.w), a3);          \
            }                                                                 \
        }                                                                     \
        v2f sv = (a0 + a1) + (a2v + a3);                                      \
        DST = sv.x + sv.y;                                                    \
    }

#define LOADW(WSEL)                                                           \
    {                                                                         \
        const float4* P4_ = (const float4*)((WSEL) + o * C64);                \
        _Pragma("unroll")                                                     \
        for (int i_ = 0; i_ < 16; ++i_) {                                     \
            float4 u_ = P4_[i_];                                              \
            wr2[2*i_+0] = mk2(u_.x, u_.y);                                    \
            wr2[2*i_+1] = mk2(u_.z, u_.w);                                    \
        }                                                                     \
        _Pragma("unroll")                                                     \
        for (int i_ = 0; i_ < 32; ++i_) asm volatile("" : "+v"(wr2[i_]));     \
    }

// ---------------------------------------------------------------------------
// prelin: 4 waves/block; wave wid computes outputs [16*wid, 16*wid+16) for
// 64 q's (lane=q). c-blocked: 32 input floats + 16 v2f acc live -> no spill.
// ---------------------------------------------------------------------------
__global__ __launch_bounds__(256, 4)
void prelin_kernel(const float* __restrict__ X, float* __restrict__ A,
                   const float* __restrict__ W, const float* __restrict__ bx,
                   const float* __restrict__ by)
{
    __shared__ float os[C64][68];
    const int p  = blockIdx.x;
    const int q0 = blockIdx.y * 64;
    const int b  = blockIdx.z;
    const int t  = threadIdx.x, wid = t >> 6, l = t & 63;
    const int q  = q0 + l;
    const int o0 = __builtin_amdgcn_readfirstlane(wid * 16);

    if (p == 0) {
        // raw passthrough of x row h=0: wave wid copies channels o0..o0+15
        const int tb = ((b * C64 + o0) * S) * S + q;
#pragma unroll
        for (int j = 0; j < 16; ++j)
            os[l][o0 + j] = X[tb + j * S * S];
    } else {
        v2f acc[16];
#pragma unroll
        for (int j = 0; j < 16; ++j) acc[j] = mk2(0.f, 0.f);
#pragma unroll
        for (int cb = 0; cb < 2; ++cb) {
            v2f vin[16];
            const int tb = ((b * C64 + cb * 32) * S + p) * S + q;
#pragma unroll
            for (int i = 0; i < 16; ++i)
                vin[i] = mk2(X[tb + (2*i) * S*S], X[tb + (2*i+1) * S*S]);
#pragma unroll
            for (int j = 0; j < 16; ++j) {
                const v2f* wr = (const v2f*)(W + (o0 + j) * C64 + cb * 32);
#pragma unroll
                for (int i = 0; i < 16; ++i)
                    acc[j] = __builtin_elementwise_fma(wr[i], vin[i], acc[j]);
            }
        }
#pragma unroll
        for (int j = 0; j < 16; ++j)
            os[l][o0 + j] = acc[j].x + acc[j].y + bx[o0 + j] + by[o0 + j];
    }
    __syncthreads();

    // store: all 4 waves; every instr covers full 64B lines
#pragma unroll
    for (int kk = 0; kk < 4; ++kk) {
        const int qq = 16 * kk + (l >> 2);
        const int oo = 16 * wid + 4 * (l & 3);
        *(float4*)(A + (((b*S + (q0+qq))*S + p) * C64 + oo)) =
            *(const float4*)&os[qq][oo];
    }
}

// ---------------------------------------------------------------------------
// scan1: v_h = relu(A1[h] + W2*v_{h-1}); stores raw v_h coalesced to hsT.
// One 64-lane wave per (b,w); no barriers; rb[16] batched broadcast reads.
// ---------------------------------------------------------------------------
__global__ __launch_bounds__(64, 2)
void scan1_kernel(const float* __restrict__ A1, float* __restrict__ hsT,
                  const float* __restrict__ W2)
{
    __shared__ float vs[2][C64];
    const int o = threadIdx.x;
    const int g = blockIdx.x, b = g / S, w = g - b * S;

    v2f wr2[32];
    LOADW(W2)

    const int abase = ((b * S + w) * S) * C64 + o;   // A1 + h*C64
    const int sb    = (b * S * S + w) * C64 + o;     // hsT + h*(S*C64)

    float v0 = A1[abase];          // raw row 0, no relu
    vs[1][o] = v0;
    hsT[sb]  = v0;
    float af[8];
#pragma unroll
    for (int h = 1; h <= 8; ++h) af[h & 7] = A1[abase + h * C64];
    __builtin_amdgcn_wave_barrier();

#define S1STEP(H, PAR)                                                        \
    {                                                                         \
        LOADRB16(&vs[PAR][0])                                                 \
        MATVEC16(s_, wr2, af[(H) & 7])                                        \
        float vnew = fmaxf(s_, 0.0f);                                         \
        vs[(PAR) ^ 1][o] = vnew;                                              \
        hsT[sb + (H) * (S * C64)] = vnew;                                     \
        int hn = (H) + 8; hn = (hn > S - 1) ? (S - 1) : hn;                   \
        af[(H) & 7] = A1[abase + hn * C64];                                   \
        __builtin_amdgcn_wave_barrier();                                      \
    }

    for (int h = 1; h < S - 1; h += 2) { S1STEP(h, 1) S1STEP(h + 1, 0) }
    S1STEP(S - 1, 1)
#undef S1STEP
}

// ---------------------------------------------------------------------------
// scan2: chunked CA+P. CA stages hsT rows coalesced and computes
// aterm = W4*row + b4 + b5 (chunk0 row0: raw). P runs the W5 recurrence with
// v_{-1}=0 and batches 16-step full-line output stores.
// ---------------------------------------------------------------------------
__global__ __launch_bounds__(128, 2)
void scan2_kernel(const float* __restrict__ hsT, float* __restrict__ out,
                  const float* __restrict__ W4, const float* __restrict__ b4,
                  const float* __restrict__ b5, const float* __restrict__ W5)
{
    __shared__ float xr[32][C64];        // raw rows (CA-private staging)
    __shared__ float xs[2][32][C64];     // aterm ring (CA -> P)
    __shared__ float vs[2][C64];         // P state double-buffer

    const int t = threadIdx.x, wid = t >> 6, o = t & 63;
    const int g = blockIdx.x, b = g / S, hr = g - b * S;

    const int hbase = ((b * S + hr) * S) * C64 + o;   // hsT + w*C64
    const int outb  = ((b * C64 + o) * S + hr) * S;   // out + w

    v2f wr2[32];
    { const float* Wsel = (wid == 0) ? W5 : W4; LOADW(Wsel) }

    float bias = 0.f;
    if (wid == 1) bias = b4[o] + b5[o];
    if (wid == 0) vs[1][o] = 0.f;        // v_{-1} = 0 trick
    float ob[16];
    __syncthreads();

    for (int ph = 0; ph < 13; ++ph) {
        if (wid == 1) {                   // ---- CA: chunk k = ph ----
            if (ph < 12) {
                const int k = ph, cb = k & 1, wb = 32 * k;
                float xg[32];
#pragma unroll
                for (int i = 0; i < 32; ++i)
                    xg[i] = hsT[hbase + (wb + i) * C64];
#pragma unroll
                for (int i = 0; i < 32; ++i)
                    xr[i][o] = xg[i];
                __builtin_amdgcn_wave_barrier();
                for (int i = 0; i < 32; ++i) {
                    MATVEC_H(a_, wr2, &xr[i][0], bias)
                    float val = (k == 0 && i == 0) ? xg[0] : a_;
                    xs[cb][i][o] = val;
                }
            }
        } else {                          // ---- P: chunk m = ph-1 ----
            if (ph >= 1) {
                const int m = ph - 1, cb = m & 1, wb = 32 * m;
                const float* xsrow = &xs[cb][0][0];
#define P2STEP(HALF, I)                                                       \
    {                                                                         \
        MATVEC_H(s_, wr2, &vs[((I) + 1) & 1][0],                              \
                 xsrow[((HALF) * 16 + (I)) * C64 + o])                        \
        float vnew = fmaxf(s_, 0.0f);                                         \
        vs[(I) & 1][o] = vnew;                                                \
        ob[I] = vnew;                                                         \
        __builtin_amdgcn_wave_barrier();                                      \
    }
#define STORE16(BASE)                                                         \
    {                                                                         \
        float4 s0 = {ob[0],  ob[1],  ob[2],  ob[3]};                          \
        float4 s1 = {ob[4],  ob[5],  ob[6],  ob[7]};                          \
        float4 s2 = {ob[8],  ob[9],  ob[10], ob[11]};                         \
        float4 s3 = {ob[12], ob[13], ob[14], ob[15]};                         \
        float4* pp = (float4*)(out + outb + (BASE));                          \
        pp[0] = s0; pp[1] = s1; pp[2] = s2; pp[3] = s3;                       \
    }
                for (int half = 0; half < 2; ++half) {
                    P2STEP(half,  0) P2STEP(half,  1) P2STEP(half,  2)
                    P2STEP(half,  3) P2STEP(half,  4) P2STEP(half,  5)
                    P2STEP(half,  6) P2STEP(half,  7) P2STEP(half,  8)
                    P2STEP(half,  9) P2STEP(half, 10) P2STEP(half, 11)
                    P2STEP(half, 12) P2STEP(half, 13) P2STEP(half, 14)
                    P2STEP(half, 15)
                    STORE16(wb + 16 * half)
                }
#undef P2STEP
#undef STORE16
            }
        }
        __syncthreads();
    }
}

extern "C" void kernel_launch(void* const* d_in, const int* in_sizes, int n_in,
                              void* d_out, int out_size, void* d_ws, size_t ws_size,
                              hipStream_t stream) {
    const float* x  = (const float*)d_in[0];
    const float* W1 = (const float*)d_in[1];
    const float* b1 = (const float*)d_in[2];
    const float* W2 = (const float*)d_in[3];
    const float* b2 = (const float*)d_in[4];
    const float* W4 = (const float*)d_in[5];
    const float* b4 = (const float*)d_in[6];
    const float* W5 = (const float*)d_in[7];
    const float* b5 = (const float*)d_in[8];
    float* out = (float*)d_out;
    float* ws  = (float*)d_ws;     // hsT: B*S*S*C floats

    // A1 -> out (scratch), hsT -> ws, final -> out.
    prelin_kernel<<<dim3(S, 6, 4), dim3(256), 0, stream>>>(x, out, W1, b1, b2);
    scan1_kernel<<<dim3(4 * S), dim3(64), 0, stream>>>(out, ws, W2);
    scan2_kernel<<<dim3(4 * S), dim3(128), 0, stream>>>(ws, out, W4, b4, b5, W5);
}

// Round 7
// 604.158 us; speedup vs baseline: 1.2867x; 1.2302x over previous
//
#include <hip/hip_runtime.h>

// UAG-RNN 4-neighbor — round 10: VMEM-free scan steps (batched IO).
//
// r6 post-mortem: VGPR=64 with weights in AGPRs (unified file, VALU reads
// AGPR directly) -> register residency was NOT the bottleneck. Remaining
// suspect: per-step global stores. A vmem store reads its data register
// asynchronously; reusing the register next step forces s_waitcnt vmcnt
// (store->L2 accept, ~400-1500cy) EVERY step. Evidence: fastest scan so far
// (r2, 197us) was the only batched-store variant; all per-step-store
// variants sit at 1790-2500 cy/step.
//
// This round: scans run 16-step batches with ZERO vmem inside steps.
//  scan1 (out->ws): v_h = relu(A1[h] + W2*v_{h-1}). The per-step rb batch
//    (broadcast of v_{h-1}) ALSO feeds the fused W4 matvec producing
//    u_{h-1} = W4*v_{h-1}+b4+b5 (w==0: raw v) held in ub[16] regs; all 16
//    stores fire in one cluster at batch end (A2[b][w][h][o]: 4KB contig).
//    af refill loads issue right after their slot is consumed (15-step
//    latency cover, never interleaved with stores).
//  scan2 (ws->out): pure W5 recurrence, v_{-1}=0 trick (no col-0 peel),
//    STORE16 dwordx4 output batches (64B/lane lines).
// Register budget <= ~240: 2 waves/SIMD -> 8 waves/CU >= 6 resident chains.
//
// prelin unchanged from r6 (isolate the scan variable).

#define C64 64
#define S   384

typedef float v2f __attribute__((ext_vector_type(2)));

static __device__ __forceinline__ v2f mk2(float a, float b) {
    v2f r; r.x = a; r.y = b; return r;
}

#define LOADW(DST, WSEL)                                                      \
    {                                                                         \
        const float4* P4_ = (const float4*)((WSEL) + o * C64);                \
        _Pragma("unroll")                                                     \
        for (int i_ = 0; i_ < 16; ++i_) {                                     \
            float4 u_ = P4_[i_];                                              \
            DST[2*i_+0] = mk2(u_.x, u_.y);                                    \
            DST[2*i_+1] = mk2(u_.z, u_.w);                                    \
        }                                                                     \
        _Pragma("unroll")                                                     \
        for (int i_ = 0; i_ < 32; ++i_) asm volatile("" : "+v"(DST[i_]));     \
    }

// ---------------------------------------------------------------------------
// prelin (r6, unchanged): A1[b][q][p][o] = W1*x[:,p,q]+b1+b2 (p>=1; p==0 raw)
// ---------------------------------------------------------------------------
__global__ __launch_bounds__(256, 4)
void prelin_kernel(const float* __restrict__ X, float* __restrict__ A,
                   const float* __restrict__ W, const float* __restrict__ bx,
                   const float* __restrict__ by)
{
    __shared__ float os[C64][68];
    const int p  = blockIdx.x;
    const int q0 = blockIdx.y * 64;
    const int b  = blockIdx.z;
    const int t  = threadIdx.x, wid = t >> 6, l = t & 63;
    const int q  = q0 + l;
    const int o0 = __builtin_amdgcn_readfirstlane(wid * 16);

    if (p == 0) {
        const int tb = ((b * C64 + o0) * S) * S + q;
#pragma unroll
        for (int j = 0; j < 16; ++j)
            os[l][o0 + j] = X[tb + j * S * S];
    } else {
        v2f acc[16];
#pragma unroll
        for (int j = 0; j < 16; ++j) acc[j] = mk2(0.f, 0.f);
#pragma unroll
        for (int cb = 0; cb < 2; ++cb) {
            v2f vin[16];
            const int tb = ((b * C64 + cb * 32) * S + p) * S + q;
#pragma unroll
            for (int i = 0; i < 16; ++i)
                vin[i] = mk2(X[tb + (2*i) * S*S], X[tb + (2*i+1) * S*S]);
#pragma unroll
            for (int j = 0; j < 16; ++j) {
                const v2f* wr = (const v2f*)(W + (o0 + j) * C64 + cb * 32);
#pragma unroll
                for (int i = 0; i < 16; ++i)
                    acc[j] = __builtin_elementwise_fma(wr[i], vin[i], acc[j]);
            }
        }
#pragma unroll
        for (int j = 0; j < 16; ++j)
            os[l][o0 + j] = acc[j].x + acc[j].y + bx[o0 + j] + by[o0 + j];
    }
    __syncthreads();

#pragma unroll
    for (int kk = 0; kk < 4; ++kk) {
        const int qq = 16 * kk + (l >> 2);
        const int oo = 16 * wid + 4 * (l & 3);
        *(float4*)(A + (((b*S + (q0+qq))*S + p) * C64 + oo)) =
            *(const float4*)&os[qq][oo];
    }
}

// ---------------------------------------------------------------------------
// scan1: vertical recurrence + fused W4 prelinear, batched IO.
// A1 layout [b][w][h][o] (from prelin); A2 layout [b][w][h][o].
// ---------------------------------------------------------------------------
__global__ __launch_bounds__(64, 2)
void scan1_kernel(const float* __restrict__ A1, float* __restrict__ A2,
                  const float* __restrict__ W2, const float* __restrict__ W4,
                  const float* __restrict__ b4, const float* __restrict__ b5)
{
    __shared__ float vs[2][C64];
    const int o = threadIdx.x;
    const int g = blockIdx.x, b = g / S, w = g - b * S;
    const bool w0 = (w == 0);

    v2f w2r[32], w4r[32];
    LOADW(w2r, W2)
    LOADW(w4r, W4)
    const float bias45 = b4[o] + b5[o];

    const int abase = ((b * S + w) * S) * C64 + o;   // + h*C64
    const float* A1p = A1 + abase;
    float*       A2p = A2 + abase;

    float af[16], ub[16];
    float v0 = A1p[0];               // h=0 raw (no relu)
    vs[0][o] = v0;
    float vcur = v0;
#pragma unroll
    for (int i = 0; i < 16; ++i) af[i] = A1p[(1 + i) * C64];
    __builtin_amdgcn_wave_barrier();

    // step H (>=1): read vs[(H-1)&1] -> u_{H-1} (W4) and v_H (W2).
    // RF: refill af[J] for the NEXT batch right after consumption.
#define SSTEP(H, J, RF)                                                       \
    {                                                                         \
        float4 rb[16];                                                        \
        {                                                                     \
            const float4* q4_ = (const float4*)&vs[((H) - 1) & 1][0];         \
            _Pragma("unroll")                                                 \
            for (int i_ = 0; i_ < 16; ++i_) rb[i_] = q4_[i_];                 \
        }                                                                     \
        v2f c0 = mk2(af[J], 0.f),  c1 = mk2(0.f,0.f),                         \
            c2 = mk2(0.f,0.f),     c3 = mk2(0.f,0.f);                         \
        v2f d0 = mk2(bias45, 0.f), d1 = mk2(0.f,0.f),                         \
            d2 = mk2(0.f,0.f),     d3 = mk2(0.f,0.f);                         \
        _Pragma("unroll")                                                     \
        for (int i_ = 0; i_ < 8; ++i_) {                                      \
            float4 r0 = rb[2*i_], r1 = rb[2*i_+1];                            \
            v2f x0 = mk2(r0.x,r0.y), x1 = mk2(r0.z,r0.w);                     \
            v2f x2 = mk2(r1.x,r1.y), x3 = mk2(r1.z,r1.w);                     \
            c0 = __builtin_elementwise_fma(w2r[4*i_+0], x0, c0);              \
            c1 = __builtin_elementwise_fma(w2r[4*i_+1], x1, c1);              \
            c2 = __builtin_elementwise_fma(w2r[4*i_+2], x2, c2);              \
            c3 = __builtin_elementwise_fma(w2r[4*i_+3], x3, c3);              \
            d0 = __builtin_elementwise_fma(w4r[4*i_+0], x0, d0);              \
            d1 = __builtin_elementwise_fma(w4r[4*i_+1], x1, d1);              \
            d2 = __builtin_elementwise_fma(w4r[4*i_+2], x2, d2);              \
            d3 = __builtin_elementwise_fma(w4r[4*i_+3], x3, d3);              \
        }                                                                     \
        v2f sc = (c0 + c1) + (c2 + c3);                                       \
        v2f sd = (d0 + d1) + (d2 + d3);                                       \
        ub[J] = w0 ? vcur : (sd.x + sd.y);                                    \
        float vn_ = fmaxf(sc.x + sc.y, 0.0f);                                 \
        vs[(H) & 1][o] = vn_;                                                 \
        vcur = vn_;                                                           \
        if (RF) {                                                             \
            int hh = (H) + 16; hh = (hh > S - 1) ? (S - 1) : hh;              \
            af[J] = A1p[hh * C64];                                            \
        }                                                                     \
    }

#define USTORE(H0)                                                            \
    _Pragma("unroll")                                                         \
    for (int j_ = 0; j_ < 16; ++j_) A2p[((H0) + j_) * C64] = ub[j_];

    // batches k=0..22: steps h=16k+1 .. 16k+16, store u[16k..16k+15]
    for (int k = 0; k < 23; ++k) {
        const int h1 = 16 * k + 1;          // odd -> (h1+j)&1 = (1+j)&1
        SSTEP(h1+ 0, 0,1) SSTEP(h1+ 1, 1,1) SSTEP(h1+ 2, 2,1)
        SSTEP(h1+ 3, 3,1) SSTEP(h1+ 4, 4,1) SSTEP(h1+ 5, 5,1)
        SSTEP(h1+ 6, 6,1) SSTEP(h1+ 7, 7,1) SSTEP(h1+ 8, 8,1)
        SSTEP(h1+ 9, 9,1) SSTEP(h1+10,10,1) SSTEP(h1+11,11,1)
        SSTEP(h1+12,12,1) SSTEP(h1+13,13,1) SSTEP(h1+14,14,1)
        SSTEP(h1+15,15,1)
        USTORE(16 * k)
    }
    // tail: steps h=369..383 (15), then epilogue u_383
    SSTEP(369, 0,0) SSTEP(370, 1,0) SSTEP(371, 2,0) SSTEP(372, 3,0)
    SSTEP(373, 4,0) SSTEP(374, 5,0) SSTEP(375, 6,0) SSTEP(376, 7,0)
    SSTEP(377, 8,0) SSTEP(378, 9,0) SSTEP(379,10,0) SSTEP(380,11,0)
    SSTEP(381,12,0) SSTEP(382,13,0) SSTEP(383,14,0)
    {   // u_383 from vs[383&1] = vs[1]
        float4 rb[16];
        {
            const float4* q4_ = (const float4*)&vs[1][0];
#pragma unroll
            for (int i_ = 0; i_ < 16; ++i_) rb[i_] = q4_[i_];
        }
        v2f d0 = mk2(bias45, 0.f), d1 = mk2(0.f,0.f),
            d2 = mk2(0.f,0.f),     d3 = mk2(0.f,0.f);
#pragma unroll
        for (int i_ = 0; i_ < 8; ++i_) {
            float4 r0 = rb[2*i_], r1 = rb[2*i_+1];
            d0 = __builtin_elementwise_fma(w4r[4*i_+0], mk2(r0.x,r0.y), d0);
            d1 = __builtin_elementwise_fma(w4r[4*i_+1], mk2(r0.z,r0.w), d1);
            d2 = __builtin_elementwise_fma(w4r[4*i_+2], mk2(r1.x,r1.y), d2);
            d3 = __builtin_elementwise_fma(w4r[4*i_+3], mk2(r1.z,r1.w), d3);
        }
        v2f sd = (d0 + d1) + (d2 + d3);
        ub[15] = w0 ? vcur : (sd.x + sd.y);
    }
    USTORE(368)
#undef SSTEP
#undef USTORE
}

// ---------------------------------------------------------------------------
// scan2: horizontal recurrence, batched IO, v_{-1}=0 trick.
// Reads A2[b][w][hr][o] (stride S*C64 per step, 256B coalesced),
// writes out[b][c][hr][w] in 16-step dwordx4 line batches.
// ---------------------------------------------------------------------------
__global__ __launch_bounds__(64, 2)
void scan2_kernel(const float* __restrict__ A2, float* __restrict__ out,
                  const float* __restrict__ W5)
{
    __shared__ float vs[2][C64];
    const int o = threadIdx.x;
    const int g = blockIdx.x, b = g / S, hr = g - b * S;

    v2f w5r[32];
    LOADW(w5r, W5)

    const float* A2p = A2 + (b * S * S + hr) * C64 + o;   // + w*(S*C64)
    const int outb  = ((b * C64 + o) * S + hr) * S;       // + w

    float af[16], ob[16];
    vs[1][o] = 0.f;                   // v_{-1} = 0  ((0-1)&1 == 1)
#pragma unroll
    for (int i = 0; i < 16; ++i) af[i] = A2p[i * (S * C64)];
    __builtin_amdgcn_wave_barrier();

#define S2STEP(WW, J, RF)                                                     \
    {                                                                         \
        float4 rb[16];                                                        \
        {                                                                     \
            const float4* q4_ = (const float4*)&vs[((WW) - 1) & 1][0];        \
            _Pragma("unroll")                                                 \
            for (int i_ = 0; i_ < 16; ++i_) rb[i_] = q4_[i_];                 \
        }                                                                     \
        v2f c0 = mk2(af[J], 0.f), c1 = mk2(0.f,0.f),                          \
            c2 = mk2(0.f,0.f),    c3 = mk2(0.f,0.f);                          \
        _Pragma("unroll")                                                     \
        for (int i_ = 0; i_ < 8; ++i_) {                                      \
            float4 r0 = rb[2*i_], r1 = rb[2*i_+1];                            \
            c0 = __builtin_elementwise_fma(w5r[4*i_+0], mk2(r0.x,r0.y), c0);  \
            c1 = __builtin_elementwise_fma(w5r[4*i_+1], mk2(r0.z,r0.w), c1);  \
            c2 = __builtin_elementwise_fma(w5r[4*i_+2], mk2(r1.x,r1.y), c2);  \
            c3 = __builtin_elementwise_fma(w5r[4*i_+3], mk2(r1.z,r1.w), c3);  \
        }                                                                     \
        v2f sc = (c0 + c1) + (c2 + c3);                                       \
        float vn_ = fmaxf(sc.x + sc.y, 0.0f);                                 \
        vs[(WW) & 1][o] = vn_;                                                \
        ob[J] = vn_;                                                          \
        if (RF) {                                                             \
            int wwn = (WW) + 16; wwn = (wwn > S - 1) ? (S - 1) : wwn;         \
            af[J] = A2p[wwn * (S * C64)];                                     \
        }                                                                     \
    }

#define STORE16(BASE)                                                         \
    {                                                                         \
        float4 s0 = {ob[0],  ob[1],  ob[2],  ob[3]};                          \
        float4 s1 = {ob[4],  ob[5],  ob[6],  ob[7]};                          \
        float4 s2 = {ob[8],  ob[9],  ob[10], ob[11]};                         \
        float4 s3 = {ob[12], ob[13], ob[14], ob[15]};                         \
        float4* pp = (float4*)(out + outb + (BASE));                          \
        pp[0] = s0; pp[1] = s1; pp[2] = s2; pp[3] = s3;                       \
    }

    // batches k=0..22 with refill; batch 23 without
    for (int k = 0; k < 23; ++k) {
        const int wb = 16 * k;              // even -> (wb+j)&1 = j&1
        S2STEP(wb+ 0, 0,1) S2STEP(wb+ 1, 1,1) S2STEP(wb+ 2, 2,1)
        S2STEP(wb+ 3, 3,1) S2STEP(wb+ 4, 4,1) S2STEP(wb+ 5, 5,1)
        S2STEP(wb+ 6, 6,1) S2STEP(wb+ 7, 7,1) S2STEP(wb+ 8, 8,1)
        S2STEP(wb+ 9, 9,1) S2STEP(wb+10,10,1) S2STEP(wb+11,11,1)
        S2STEP(wb+12,12,1) S2STEP(wb+13,13,1) S2STEP(wb+14,14,1)
        S2STEP(wb+15,15,1)
        STORE16(wb)
    }
    S2STEP(368, 0,0) S2STEP(369, 1,0) S2STEP(370, 2,0) S2STEP(371, 3,0)
    S2STEP(372, 4,0) S2STEP(373, 5,0) S2STEP(374, 6,0) S2STEP(375, 7,0)
    S2STEP(376, 8,0) S2STEP(377, 9,0) S2STEP(378,10,0) S2STEP(379,11,0)
    S2STEP(380,12,0) S2STEP(381,13,0) S2STEP(382,14,0) S2STEP(383,15,0)
    STORE16(368)
#undef S2STEP
#undef STORE16
}

extern "C" void kernel_launch(void* const* d_in, const int* in_sizes, int n_in,
                              void* d_out, int out_size, void* d_ws, size_t ws_size,
                              hipStream_t stream) {
    const float* x  = (const float*)d_in[0];
    const float* W1 = (const float*)d_in[1];
    const float* b1 = (const float*)d_in[2];
    const float* W2 = (const float*)d_in[3];
    const float* b2 = (const float*)d_in[4];
    const float* W4 = (const float*)d_in[5];
    const float* b4 = (const float*)d_in[6];
    const float* W5 = (const float*)d_in[7];
    const float* b5 = (const float*)d_in[8];
    float* out = (float*)d_out;
    float* ws  = (float*)d_ws;     // A2: B*S*S*C floats

    // x -> A1(out) -> scan1 -> A2(ws) -> scan2 -> out
    prelin_kernel<<<dim3(S, 6, 4), dim3(256), 0, stream>>>(x, out, W1, b1, b2);
    scan1_kernel<<<dim3(4 * S), dim3(64), 0, stream>>>(out, ws, W2, W4, b4, b5);
    scan2_kernel<<<dim3(4 * S), dim3(64), 0, stream>>>(ws, out, W5);
}